// Round 5
// baseline (254.353 us; speedup 1.0000x reference)
//
#include <hip/hip_runtime.h>
#include <hip/hip_bf16.h>
#include <stdint.h>
#include <stddef.h>

// ---- problem constants ----
static constexpr int Bb = 8, Ss = 1024, Ee = 1024, Hh = 16, Dd = 64;
static constexpr int Mm = Bb * Ss;            // 8192 rows
// per-(b,h) block of Q/K/V is contiguous [1024 x 64] at offset bh*65536 (reshape quirk)

typedef __attribute__((ext_vector_type(8))) short frag8;   // 8 x bf16 (4 VGPRs)
typedef __attribute__((ext_vector_type(4))) float fx4;     // 4 x f32 accumulator
typedef __attribute__((ext_vector_type(4))) short s4v;     // 4 x bf16 (8 B)

#define GP(p) ((const __attribute__((address_space(1))) void*)(p))
#define LP(p) ((__attribute__((address_space(3))) void*)(p))

static constexpr float QSC = 0.045084220027780106f;  // log2(e)/32: E^-0.5 + ln->log2, folded into Q

__device__ inline short f2bf(float x) {  // round-to-nearest-even fp32 -> bf16 bits
  union { float f; unsigned u; } c; c.f = x;
  unsigned u = c.u;
  unsigned r = (u + 0x7FFFu + ((u >> 16) & 1u)) >> 16;
  return (short)r;
}

// ---------------- fp32 -> bf16 elementwise (vectorized x4) ----------------
__global__ __launch_bounds__(256) void cvt_kernel(const float* __restrict__ in,
                                                  short* __restrict__ out, int n4) {
  int i = blockIdx.x * 256 + threadIdx.x;
  if (i >= n4) return;
  float4 v = *((const float4*)in + i);
  union { short s[4]; uint2 u; } o;
  o.s[0] = f2bf(v.x); o.s[1] = f2bf(v.y); o.s[2] = f2bf(v.z); o.s[3] = f2bf(v.w);
  *(uint2*)(out + (size_t)i * 4) = o.u;
}

// ------- transpose+convert 4 weights fp32 [K][N] -> bf16 [N][K] (z selects weight) -------
__global__ __launch_bounds__(256) void transpose_cvt4(const float* __restrict__ w0,
                                                      const float* __restrict__ w1,
                                                      const float* __restrict__ w2,
                                                      const float* __restrict__ w3,
                                                      short* __restrict__ WtBase) {
  __shared__ short tile[32][33];
  const int z = blockIdx.z;
  const float* W = z == 0 ? w0 : (z == 1 ? w1 : (z == 2 ? w2 : w3));
  short* Wt = WtBase + (size_t)z * 1024 * 1024;
  const int bx = blockIdx.x * 32;  // n
  const int by = blockIdx.y * 32;  // k
  const int tx = threadIdx.x & 31, ty = threadIdx.x >> 5;  // 32 x 8
  #pragma unroll
  for (int j = 0; j < 32; j += 8)
    tile[ty + j][tx] = f2bf(W[(size_t)(by + ty + j) * 1024 + bx + tx]);
  __syncthreads();
  #pragma unroll
  for (int j = 0; j < 32; j += 8)
    Wt[(size_t)(bx + ty + j) * 1024 + by + tx] = tile[tx][ty + j];
}

// ------------- per-head transpose V [bh][1024 s][64 d] -> Vt [bh][64 d][1024 s] -------------
__global__ __launch_bounds__(256) void transpose_v(const short* __restrict__ V,
                                                   short* __restrict__ Vt) {
  __shared__ short tile[64][65];
  const int bh = blockIdx.y;
  const int s0 = blockIdx.x * 64;
  const short* Vb = V + (size_t)bh * 65536;
  short* Vtb = Vt + (size_t)bh * 65536;
  const int tx = threadIdx.x & 63, ty = threadIdx.x >> 6;  // 64 x 4
  #pragma unroll
  for (int j = 0; j < 64; j += 4)
    tile[ty + j][tx] = Vb[(size_t)(s0 + ty + j) * 64 + tx];
  __syncthreads();
  #pragma unroll
  for (int j = 0; j < 64; j += 4)
    Vtb[(size_t)(ty + j) * 1024 + s0 + tx] = tile[tx][ty + j];
}

// ================= QKV GEMM: 256x256 tile, BK=64, 8-phase schedule =================
// C = A[8192x1024] * Bt[3072x1024]^T, output split into Q/K/V bf16 (Q scaled by QSC).
// 8 waves as 4M x 2N: per-wave C = 64 rows x 128 cols (4 m-frags x 8 n-frags).
// Per K-tile, 4 phases: phase p computes n-frags {2p,2p+1} (16 MFMA). A-frags (8 b128)
// read once per K-tile in phase 0; B-quadrant (4 b128) per phase. LDS XOR-swizzle
// (chunk ^= row&7) on read + pre-swizzled global source (linear DMA dest, rule #21).
// v4 (resubmit; round-4 bench was an infra failure, kernel never ran):
// NO mid-tile vmcnt waits (r2's 4-per-tile waits resynced all 8 waves to the DMA
// timeline 4x/tile, collapsing the wave stagger that lets ds_read overlap MFMA across
// waves -> 30% MfmaUtil; r3 showed more slack doesn't help, so waits were the cost).
// All 8 stage loads for tile t+1 issue in ph0 of tile t (>=3.5 phases of slack);
// ONE vmcnt(0)+barrier at the K-tile boundary. Within-tile phases have barriers only.
// LDS = 2 x (32KB A + 32KB B) = 128KB -> 1 block/CU (8 waves).
__global__ __launch_bounds__(512, 2) void gemm_qkv_8ph(const short* __restrict__ A,
                                                       const short* __restrict__ Bt,
                                                       short* __restrict__ Cq,
                                                       short* __restrict__ Ck,
                                                       short* __restrict__ Cv) {
  __shared__ short As[2][16384];
  __shared__ short Bs[2][16384];
  const int t = threadIdx.x;
  const int w = t >> 6, lane = t & 63;
  const int fm = lane & 15, quad = lane >> 4;
  const int wm = w >> 1, wn = w & 1;            // 4M x 2N waves
  // XCD-aware swizzle: nwg=384, 384%8==0 -> simple bijective form
  const int wg = (blockIdx.x & 7) * 48 + (blockIdx.x >> 3);
  const int nt_i = wg % 12, mt_i = wg / 12;     // consecutive wg share A-panel, walk B
  const int m0 = mt_i * 256, n0 = nt_i * 256;

  // ---- staging source offsets (pre-swizzled global; LDS dest is linear) ----
  // A tile: [256 rows][8 chunks of 16B]; load i covers chunks i*512+t.
  // B tile LDS layout: [4 units][2 halves][32 rows][8 chunks]; unit j = n-rows
  //   {j*32..+32} u {128+j*32..+32} (what phase j's B-quadrant reads).
  int goffA[4], goffB[4];
  #pragma unroll
  for (int i = 0; i < 4; ++i) {
    int c = i * 512 + t, row = c >> 3, col8 = (c & 7) ^ (row & 7);
    goffA[i] = row * 1024 + col8 * 8;
  }
  {
    int row32 = (t >> 3) & 31, hv = t >> 8, col8 = (t & 7) ^ (row32 & 7);
    #pragma unroll
    for (int j = 0; j < 4; ++j)
      goffB[j] = (hv * 128 + j * 32 + row32) * 1024 + col8 * 8;
  }
  const short* Ag = A + (size_t)m0 * 1024;
  const short* Bg = Bt + (size_t)n0 * 1024;

  fx4 acc[4][8];
  #pragma unroll
  for (int i = 0; i < 4; ++i)
    #pragma unroll
    for (int j = 0; j < 8; ++j) acc[i][j] = (fx4){0.f, 0.f, 0.f, 0.f};

  // ---- read-side constants (short offsets; chunk = 8 shorts) ----
  const int s0o = ((0 * 4 + quad) ^ (fm & 7)) * 8;   // kk=0 swizzled chunk
  const int s1o = ((1 * 4 + quad) ^ (fm & 7)) * 8;   // kk=1
  const int aBase = (wm * 64 + fm) * 64;             // + mf*1024 + s?o
  const int bBase = wn * 2048 + fm * 64;             // + unit*4096 + (nf&1)*1024 + s?o

#define STG_A(i, koff, dstbuf) \
  __builtin_amdgcn_global_load_lds(GP(Ag + (koff) + goffA[i]), \
                                   LP((dstbuf) + ((i) * 512 + t) * 8), 16, 0, 0)
#define STG_B(j, koff, dstbuf) \
  __builtin_amdgcn_global_load_lds(GP(Bg + (koff) + goffB[j]), \
                                   LP((dstbuf) + ((j) * 512 + t) * 8), 16, 0, 0)
#define LOAD_B(p) \
  { const short* bp = Bb + (p) * 4096 + bBase; \
    bf[0][0] = *(const frag8*)(bp + s0o); \
    bf[0][1] = *(const frag8*)(bp + s1o); \
    bf[1][0] = *(const frag8*)(bp + 1024 + s0o); \
    bf[1][1] = *(const frag8*)(bp + 1024 + s1o); }
#define MFMA_PH(p) \
  __builtin_amdgcn_s_barrier(); \
  asm volatile("s_waitcnt lgkmcnt(0)" ::: "memory"); \
  __builtin_amdgcn_s_setprio(1); \
  _Pragma("unroll") \
  for (int mf = 0; mf < 4; ++mf) { \
    acc[mf][2*(p)]   = __builtin_amdgcn_mfma_f32_16x16x32_bf16(af[mf][0], bf[0][0], acc[mf][2*(p)],   0, 0, 0); \
    acc[mf][2*(p)]   = __builtin_amdgcn_mfma_f32_16x16x32_bf16(af[mf][1], bf[0][1], acc[mf][2*(p)],   0, 0, 0); \
    acc[mf][2*(p)+1] = __builtin_amdgcn_mfma_f32_16x16x32_bf16(af[mf][0], bf[1][0], acc[mf][2*(p)+1], 0, 0, 0); \
    acc[mf][2*(p)+1] = __builtin_amdgcn_mfma_f32_16x16x32_bf16(af[mf][1], bf[1][1], acc[mf][2*(p)+1], 0, 0, 0); \
  } \
  __builtin_amdgcn_s_setprio(0);

  // ---- prologue: stage tile 0 into buffer 0, full drain once ----
  #pragma unroll
  for (int i = 0; i < 4; ++i) STG_A(i, 0, &As[0][0]);
  #pragma unroll
  for (int j = 0; j < 4; ++j) STG_B(j, 0, &Bs[0][0]);
  asm volatile("s_waitcnt vmcnt(0)" ::: "memory");
  __builtin_amdgcn_s_barrier();

  for (int kt = 0; kt < 16; ++kt) {
    const short* Ab = As[kt & 1];
    const short* Bb = Bs[kt & 1];
    short* An = (short*)As[(kt & 1) ^ 1];
    short* Bn = (short*)Bs[(kt & 1) ^ 1];
    const int kn = (kt + 1) * 64;
    const bool pf = kt < 15;
    frag8 af[4][2], bf[2][2];

    // ---- phase 0: A frags (8 b128) + B unit 0 (4 b128); stage ALL of tile t+1 ----
    #pragma unroll
    for (int mf = 0; mf < 4; ++mf) {
      const short* ap = Ab + aBase + mf * 1024;
      af[mf][0] = *(const frag8*)(ap + s0o);
      af[mf][1] = *(const frag8*)(ap + s1o);
    }
    LOAD_B(0);
    if (pf) {
      STG_A(0, kn, An); STG_A(1, kn, An); STG_A(2, kn, An); STG_A(3, kn, An);
      STG_B(0, kn, Bn); STG_B(1, kn, Bn); STG_B(2, kn, Bn); STG_B(3, kn, Bn);
    }
    MFMA_PH(0);
    __builtin_amdgcn_s_barrier();     // no wait: B1-B3 guaranteed since tile start

    // ---- phase 1: B unit 1 ----
    LOAD_B(1);
    MFMA_PH(1);
    __builtin_amdgcn_s_barrier();

    // ---- phase 2: B unit 2 ----
    LOAD_B(2);
    MFMA_PH(2);
    __builtin_amdgcn_s_barrier();

    // ---- phase 3: B unit 3; K-tile boundary = the ONLY vmcnt wait ----
    LOAD_B(3);
    MFMA_PH(3);
    if (pf) {  // t+1's 8 loads issued 3.5 phases ago -> drain is cheap, happens 1x/tile
      asm volatile("s_waitcnt vmcnt(0)" ::: "memory");
      __builtin_amdgcn_s_barrier();
    }
  }
#undef STG_A
#undef STG_B
#undef LOAD_B
#undef MFMA_PH

  // ---- epilogue: split into Q/K/V, Q scaled by QSC ----
  const int nb = n0 >> 10;                       // 256-tile never crosses 1024 boundary
  short* dst = nb == 0 ? Cq : (nb == 1 ? Ck : Cv);
  const float scl = (nb == 0) ? QSC : 1.0f;
  const int nl0 = (n0 & 1023) + wn * 128;
  const int rbase = m0 + wm * 64 + quad * 4;
  #pragma unroll
  for (int mf = 0; mf < 4; ++mf)
    #pragma unroll
    for (int nf = 0; nf < 8; ++nf)
      #pragma unroll
      for (int r = 0; r < 4; ++r) {
        int row = rbase + mf * 16 + r;
        int col = nl0 + nf * 16 + fm;
        dst[(size_t)row * 1024 + col] = f2bf(acc[mf][nf][r] * scl);
      }
}

// ------------- bf16 GEMM: C = A[MxK] * Bt[NxK]^T  (m97-style 128x128 tile) -------------
// MODE 1 only now: f32 output + bias (final projection; N=1024 -> 256^2 packs badly).
template <int MODE>
__global__ __launch_bounds__(256) void gemm_bt(const short* __restrict__ A,
                                               const short* __restrict__ Bt,
                                               void* __restrict__ C0,
                                               void* __restrict__ C1,
                                               void* __restrict__ C2,
                                               const float* __restrict__ bias,
                                               int M, int N, int K) {
  __shared__ short As[128 * 32];
  __shared__ short Bs[128 * 32];
  const int t = threadIdx.x;
  const int w = t >> 6, lane = t & 63;
  const int fm = lane & 15, quad = lane >> 4;
  const int m0 = blockIdx.y * 128, n0 = blockIdx.x * 128;
  const int wm = (w >> 1) * 64, wn = (w & 1) * 64;
  fx4 acc[4][4];
  #pragma unroll
  for (int i = 0; i < 4; ++i)
    #pragma unroll
    for (int j = 0; j < 4; ++j) acc[i][j] = (fx4){0.f, 0.f, 0.f, 0.f};

  for (int k0 = 0; k0 < K; k0 += 32) {
    #pragma unroll
    for (int i = 0; i < 2; ++i) {
      int chunk = i * 256 + t;            // 512 chunks of 16B per tile
      int row = chunk >> 2, cc = chunk & 3;
      __builtin_amdgcn_global_load_lds(GP(A + (size_t)(m0 + row) * K + k0 + cc * 8),
                                       LP(As + chunk * 8), 16, 0, 0);
      __builtin_amdgcn_global_load_lds(GP(Bt + (size_t)(n0 + row) * K + k0 + cc * 8),
                                       LP(Bs + chunk * 8), 16, 0, 0);
    }
    __syncthreads();
    frag8 af[4], bfr[4];
    #pragma unroll
    for (int mt = 0; mt < 4; ++mt)
      af[mt] = *(const frag8*)(As + (wm + mt * 16 + fm) * 32 + quad * 8);
    #pragma unroll
    for (int nt = 0; nt < 4; ++nt)
      bfr[nt] = *(const frag8*)(Bs + (wn + nt * 16 + fm) * 32 + quad * 8);
    #pragma unroll
    for (int mt = 0; mt < 4; ++mt)
      #pragma unroll
      for (int nt = 0; nt < 4; ++nt)
        acc[mt][nt] = __builtin_amdgcn_mfma_f32_16x16x32_bf16(af[mt], bfr[nt], acc[mt][nt], 0, 0, 0);
    __syncthreads();
  }
  #pragma unroll
  for (int mt = 0; mt < 4; ++mt)
    #pragma unroll
    for (int nt = 0; nt < 4; ++nt)
      #pragma unroll
      for (int r = 0; r < 4; ++r) {
        int row = m0 + wm + mt * 16 + quad * 4 + r;
        int col = n0 + wn + nt * 16 + fm;
        ((float*)C0)[(size_t)row * N + col] = acc[mt][nt][r] + bias[col];
      }
}

// ------------- attention v5: 64 q-rows per WAVE (256 per block), S^T trick -------------
// K/V tiles double-buffered; one __syncthreads per chunk (staging latency hidden under
// the previous chunk's QK^T+exp+PV compute).
__global__ __launch_bounds__(256, 2) void attn_kernel(const short* __restrict__ Q,
                                                      const short* __restrict__ K,
                                                      const short* __restrict__ Vt,
                                                      short* __restrict__ Ctx) {
  __shared__ short Ks[2][4096];       // 64 keys x 64 d, fragment-ordered (2 x 8 KB)
  __shared__ short Vs[2][4096];       // 64 d x 64 keys, fragment-ordered (2 x 8 KB)
  __shared__ short Plds[4 * 64 * 72]; // per-wave 64q x 64key, stride 72 (36 KB)
  const int bh = blockIdx.x, qt = blockIdx.y;
  const int t = threadIdx.x;
  const int w = t >> 6, lane = t & 63;
  const int fm = lane & 15, quad = lane >> 4;
  const short* Qb = Q + (size_t)bh * 65536;
  const short* Kb = K + (size_t)bh * 65536;
  const short* Vb = Vt + (size_t)bh * 65536;
  const int q0 = qt * 256 + w * 64;
  short* myP = Plds + w * 4608;

  frag8 qb[4][2];
  #pragma unroll
  for (int g = 0; g < 4; ++g)
    #pragma unroll
    for (int h = 0; h < 2; ++h)
      qb[g][h] = *(const frag8*)(Qb + (size_t)(q0 + g * 16 + fm) * 64 + h * 32 + quad * 8);

  fx4 O[4][4];
  #pragma unroll
  for (int g = 0; g < 4; ++g)
    #pragma unroll
    for (int nt = 0; nt < 4; ++nt) O[g][nt] = (fx4){0.f, 0.f, 0.f, 0.f};
  float lp[4] = {0.f, 0.f, 0.f, 0.f};

  int koff[2], voff[2], loff[2];
  #pragma unroll
  for (int i = 0; i < 2; ++i) {
    int c = i * 256 + t;
    int cf = c & 15, cq = (c >> 4) & 3, ch = (c >> 6) & 1, cg = c >> 7;
    koff[i] = (cg * 16 + cf) * 64 + ch * 32 + cq * 8;     // + key0*64
    voff[i] = (cg * 16 + cf) * 1024 + ch * 32 + cq * 8;   // + key0
    loff[i] = c * 8;
  }

  #pragma unroll
  for (int i = 0; i < 2; ++i) {
    __builtin_amdgcn_global_load_lds(GP(Kb + koff[i]), LP(&Ks[0][0] + loff[i]), 16, 0, 0);
    __builtin_amdgcn_global_load_lds(GP(Vb + voff[i]), LP(&Vs[0][0] + loff[i]), 16, 0, 0);
  }
  __syncthreads();

  for (int c = 0; c < 16; ++c) {
    const int cur = c & 1;
    if (c < 15) {
      const int key0n = (c + 1) * 64;
      #pragma unroll
      for (int i = 0; i < 2; ++i) {
        __builtin_amdgcn_global_load_lds(GP(Kb + (size_t)key0n * 64 + koff[i]),
                                         LP(&Ks[cur ^ 1][0] + loff[i]), 16, 0, 0);
        __builtin_amdgcn_global_load_lds(GP(Vb + (size_t)key0n + voff[i]),
                                         LP(&Vs[cur ^ 1][0] + loff[i]), 16, 0, 0);
      }
    }
    const short* Kc = &Ks[cur][0];
    const short* Vc = &Vs[cur][0];

    #pragma unroll
    for (int s = 0; s < 4; ++s) {
      frag8 k0 = *(const frag8*)(Kc + (s * 2 + 0) * 512 + lane * 8);
      frag8 k1 = *(const frag8*)(Kc + (s * 2 + 1) * 512 + lane * 8);
      #pragma unroll
      for (int g = 0; g < 4; ++g) {
        fx4 z = (fx4){0.f, 0.f, 0.f, 0.f};
        z = __builtin_amdgcn_mfma_f32_16x16x32_bf16(k0, qb[g][0], z, 0, 0, 0);
        z = __builtin_amdgcn_mfma_f32_16x16x32_bf16(k1, qb[g][1], z, 0, 0, 0);
        s4v pv;
        #pragma unroll
        for (int r = 0; r < 4; ++r) {
          float p = __builtin_amdgcn_exp2f(z[r]);
          lp[g] += p;
          union { float f; unsigned u; } cv; cv.f = p;
          pv[r] = (short)(cv.u >> 16);
        }
        *(s4v*)(myP + (g * 16 + fm) * 72 + s * 16 + quad * 4) = pv;
      }
    }
    asm volatile("s_waitcnt lgkmcnt(0)" ::: "memory");
    #pragma unroll
    for (int h = 0; h < 2; ++h) {
      frag8 pf[4];
      #pragma unroll
      for (int g = 0; g < 4; ++g)
        pf[g] = *(const frag8*)(myP + (g * 16 + fm) * 72 + h * 32 + quad * 8);
      #pragma unroll
      for (int nt = 0; nt < 4; ++nt) {
        frag8 vf = *(const frag8*)(Vc + (nt * 2 + h) * 512 + lane * 8);
        #pragma unroll
        for (int g = 0; g < 4; ++g)
          O[g][nt] = __builtin_amdgcn_mfma_f32_16x16x32_bf16(pf[g], vf, O[g][nt], 0, 0, 0);
      }
    }
    __syncthreads();
  }

  float rl[4][4];
  #pragma unroll
  for (int g = 0; g < 4; ++g) {
    float v = lp[g];
    v += __shfl_xor(v, 16, 64);
    v += __shfl_xor(v, 32, 64);
    float inv = 1.f / v;
    #pragma unroll
    for (int r = 0; r < 4; ++r) rl[g][r] = __shfl(inv, quad * 4 + r, 16);
  }
  const int b = bh >> 4, h = bh & 15;
  #pragma unroll
  for (int g = 0; g < 4; ++g)
    #pragma unroll
    for (int nt = 0; nt < 4; ++nt)
      #pragma unroll
      for (int r = 0; r < 4; ++r) {
        int row = b * 1024 + q0 + g * 16 + quad * 4 + r;  // gathered: [b*S+s][h*64+d]
        int col = h * 64 + nt * 16 + fm;
        Ctx[(size_t)row * 1024 + col] = f2bf(O[g][nt][r] * rl[g][r]);
      }
}

extern "C" void kernel_launch(void* const* d_in, const int* in_sizes, int n_in,
                              void* d_out, int out_size, void* d_ws, size_t ws_size,
                              hipStream_t stream) {
  const float* hs = (const float*)d_in[0];
  const float* wq = (const float*)d_in[1];
  const float* wk = (const float*)d_in[2];
  const float* wv = (const float*)d_in[3];
  const float* wo = (const float*)d_in[4];
  const float* bo = (const float*)d_in[5];
  float* out = (float*)d_out;

  char* wp = (char*)d_ws;
  const size_t MB16 = (size_t)Mm * Ee * 2;   // 16 MiB
  const size_t MB2  = (size_t)Ee * Ee * 2;   // 2 MiB
  short* Xb  = (short*)wp; wp += MB16;
  short* Wqt = (short*)wp; wp += MB2;   // Wqt/Wkt/Wvt/Wot contiguous = [4096][1024]
  short* Wkt = (short*)wp; wp += MB2;
  short* Wvt = (short*)wp; wp += MB2;
  short* Wot = (short*)wp; wp += MB2;
  short* Qb  = (short*)wp; wp += MB16;
  short* Kb  = (short*)wp; wp += MB16;
  short* Vb  = (short*)wp; wp += MB16;
  short* Vt  = (short*)wp; wp += MB16;
  short* Ctx = (short*)wp; wp += MB16;

  // 1. hidden -> bf16
  cvt_kernel<<<(Mm * Ee / 4 + 255) / 256, 256, 0, stream>>>(hs, Xb, Mm * Ee / 4);
  // 2. all 4 weights -> bf16 transposed [out][in], one launch
  transpose_cvt4<<<dim3(32, 32, 4), 256, 0, stream>>>(wq, wk, wv, wo, Wqt);
  // 3. fused QKV projection: 256^2 8-phase GEMM, single boundary vmcnt (Q scaled by QSC)
  gemm_qkv_8ph<<<384, 512, 0, stream>>>(Xb, Wqt, Qb, Kb, Vb);
  // 4. V -> Vt per head
  transpose_v<<<dim3(16, 128), 256, 0, stream>>>(Vb, Vt);
  // 5. attention -> gathered ctx (bf16); grid x=bh keeps same-bh blocks on one XCD
  attn_kernel<<<dim3(128, 4), 256, 0, stream>>>(Qb, Kb, Vt, Ctx);
  // 6. output projection + bias (fp32 out)
  gemm_bt<1><<<dim3(8, 64), 256, 0, stream>>>(Ctx, Wot, out, nullptr, nullptr, bo, Mm, Ee, Ee);
}

// Round 6
// 250.971 us; speedup vs baseline: 1.0135x; 1.0135x over previous
//
#include <hip/hip_runtime.h>
#include <hip/hip_bf16.h>
#include <stdint.h>
#include <stddef.h>

// ---- problem constants ----
static constexpr int Bb = 8, Ss = 1024, Ee = 1024, Hh = 16, Dd = 64;
static constexpr int Mm = Bb * Ss;            // 8192 rows
// per-(b,h) block of Q/K/V is contiguous [1024 x 64] at offset bh*65536 (reshape quirk)

typedef __attribute__((ext_vector_type(8))) short frag8;   // 8 x bf16 (4 VGPRs)
typedef __attribute__((ext_vector_type(4))) float fx4;     // 4 x f32 accumulator
typedef __attribute__((ext_vector_type(4))) short s4v;     // 4 x bf16 (8 B)

#define GP(p) ((const __attribute__((address_space(1))) void*)(p))
#define LP(p) ((__attribute__((address_space(3))) void*)(p))

static constexpr float QSC = 0.045084220027780106f;  // log2(e)/32: E^-0.5 + ln->log2, folded into Q

__device__ inline short f2bf(float x) {  // round-to-nearest-even fp32 -> bf16 bits
  union { float f; unsigned u; } c; c.f = x;
  unsigned u = c.u;
  unsigned r = (u + 0x7FFFu + ((u >> 16) & 1u)) >> 16;
  return (short)r;
}

// ---------------- fp32 -> bf16 elementwise (vectorized x4) ----------------
__global__ __launch_bounds__(256) void cvt_kernel(const float* __restrict__ in,
                                                  short* __restrict__ out, int n4) {
  int i = blockIdx.x * 256 + threadIdx.x;
  if (i >= n4) return;
  float4 v = *((const float4*)in + i);
  union { short s[4]; uint2 u; } o;
  o.s[0] = f2bf(v.x); o.s[1] = f2bf(v.y); o.s[2] = f2bf(v.z); o.s[3] = f2bf(v.w);
  *(uint2*)(out + (size_t)i * 4) = o.u;
}

// ------- transpose+convert 4 weights fp32 [K][N] -> bf16 [N][K] (z selects weight) -------
__global__ __launch_bounds__(256) void transpose_cvt4(const float* __restrict__ w0,
                                                      const float* __restrict__ w1,
                                                      const float* __restrict__ w2,
                                                      const float* __restrict__ w3,
                                                      short* __restrict__ WtBase) {
  __shared__ short tile[32][33];
  const int z = blockIdx.z;
  const float* W = z == 0 ? w0 : (z == 1 ? w1 : (z == 2 ? w2 : w3));
  short* Wt = WtBase + (size_t)z * 1024 * 1024;
  const int bx = blockIdx.x * 32;  // n
  const int by = blockIdx.y * 32;  // k
  const int tx = threadIdx.x & 31, ty = threadIdx.x >> 5;  // 32 x 8
  #pragma unroll
  for (int j = 0; j < 32; j += 8)
    tile[ty + j][tx] = f2bf(W[(size_t)(by + ty + j) * 1024 + bx + tx]);
  __syncthreads();
  #pragma unroll
  for (int j = 0; j < 32; j += 8)
    Wt[(size_t)(bx + ty + j) * 1024 + by + tx] = tile[tx][ty + j];
}

// ------------- per-head transpose V [bh][1024 s][64 d] -> Vt [bh][64 d][1024 s] -------------
__global__ __launch_bounds__(256) void transpose_v(const short* __restrict__ V,
                                                   short* __restrict__ Vt) {
  __shared__ short tile[64][65];
  const int bh = blockIdx.y;
  const int s0 = blockIdx.x * 64;
  const short* Vb = V + (size_t)bh * 65536;
  short* Vtb = Vt + (size_t)bh * 65536;
  const int tx = threadIdx.x & 63, ty = threadIdx.x >> 6;  // 64 x 4
  #pragma unroll
  for (int j = 0; j < 64; j += 4)
    tile[ty + j][tx] = Vb[(size_t)(s0 + ty + j) * 64 + tx];
  __syncthreads();
  #pragma unroll
  for (int j = 0; j < 64; j += 4)
    Vtb[(size_t)(ty + j) * 1024 + s0 + tx] = tile[tx][ty + j];
}

// ================= QKV GEMM v5: 128x256 tile, BK=64, v2-style counted schedule ==========
// C = A[8192x1024] * Bt[3072x1024]^T, output split into Q/K/V bf16 (Q scaled by QSC).
// v5 rationale: v2 (65us, spread staging + counted mid-tile waits) is the best of the
// schedule family (v3/v4 deviations both regressed) -> keep its semantics, fix the GRID
// QUANTIZATION instead: 384 blocks @ 1/CU = 1.5 rounds = 75% ceiling. Halve M-tile:
// 128x256 -> grid 64x12 = 768 blocks = EXACTLY 3 rounds (ideal 1.33x).
// 8 waves as 2M x 4N: per-wave C = 64x64 (4 m-frags x 4 n-frags, acc=64 VGPR).
// Per K-tile, 2 phases of 16 MFMA (same phase shape as v2's ph0/ph1):
//   ph0: read A frags (8 b128) + B-unit0 (4 b128); stage next A (2) + B-unit0' (2)
//   ph1: read B-unit1 (4 b128);                    stage next B-unit1' (2)
// B LDS layout: unit u holds n-rows with (n>>5)&1==u (what phase u reads), 128 rows ea.
// LDS XOR-swizzle (chunk ^= row&7) on read + pre-swizzled global source (rule #21).
// Counted waits (FIFO-derived, wait-then-barrier like v2; never 0 in steady loop):
//   end ph0 -> vmcnt(4)  [B-unit1 of CURRENT tile, issued 1.5 phases ago]
//   end ph1 -> vmcnt(2)  [next tile's A + B-unit0; leaves B-unit1' in flight]
// LDS = 2 x (16KB A + 32KB B) = 96KB -> 1 block/CU (8 waves).
__global__ __launch_bounds__(512, 2) void gemm_qkv_8ph(const short* __restrict__ A,
                                                       const short* __restrict__ Bt,
                                                       short* __restrict__ Cq,
                                                       short* __restrict__ Ck,
                                                       short* __restrict__ Cv) {
  __shared__ short As[2][8192];    // [128 rows][64 shorts] linear, 16KB per buf
  __shared__ short Bs[2][16384];   // [2 units][128 rows][64 shorts], 32KB per buf
  const int t = threadIdx.x;
  const int w = t >> 6, lane = t & 63;
  const int fm = lane & 15, quad = lane >> 4;
  const int wm = w >> 2, wn = w & 3;            // 2M x 4N waves
  // XCD-aware swizzle: nwg=768, 768%8==0 -> simple bijective form (cpx=96)
  const int wg = (blockIdx.x & 7) * 96 + (blockIdx.x >> 3);
  const int nt_i = wg % 12, mt_i = wg / 12;     // consecutive wg share A-panel, walk B
  const int m0 = mt_i * 128, n0 = nt_i * 256;

  // ---- staging source offsets (pre-swizzled global; LDS dest is linear) ----
  // A tile: [128 rows][8 chunks of 16B]; load i covers chunks i*512+t (1024 chunks).
  // B unit u: unit-local row r in [0,128) -> global n = (r>>5)*64 + u*32 + (r&31);
  //   load j = u*2+i covers unit-u chunks i*512+t.
  int goffA[2], goffB[4];
  #pragma unroll
  for (int i = 0; i < 2; ++i) {
    int c = i * 512 + t, row = c >> 3, col8 = (c & 7) ^ (row & 7);
    goffA[i] = row * 1024 + col8 * 8;
  }
  #pragma unroll
  for (int j = 0; j < 4; ++j) {
    int u = j >> 1, i = j & 1;
    int c = i * 512 + t, r = c >> 3, col8 = (c & 7) ^ (r & 7);
    int n = (r >> 5) * 64 + u * 32 + (r & 31);
    goffB[j] = n * 1024 + col8 * 8;
  }
  const short* Ag = A + (size_t)m0 * 1024;
  const short* Bg = Bt + (size_t)n0 * 1024;

  fx4 acc[4][4];
  #pragma unroll
  for (int i = 0; i < 4; ++i)
    #pragma unroll
    for (int j = 0; j < 4; ++j) acc[i][j] = (fx4){0.f, 0.f, 0.f, 0.f};

  // ---- read-side constants (short offsets; chunk = 8 shorts) ----
  const int s0o = (quad ^ (fm & 7)) * 8;         // kk=0 swizzled chunk
  const int s1o = ((4 + quad) ^ (fm & 7)) * 8;   // kk=1
  const int aBase = (wm * 64 + fm) * 64;         // + mf*1024 + s?o
  const int bBase = (wn * 32 + fm) * 64;         // + p*8192 + e*16*64 + s?o

#define STG_A(i, koff, dstbuf) \
  __builtin_amdgcn_global_load_lds(GP(Ag + (koff) + goffA[i]), \
                                   LP((dstbuf) + ((i) * 512 + t) * 8), 16, 0, 0)
#define STG_B(j, koff, dstbuf) \
  __builtin_amdgcn_global_load_lds(GP(Bg + (koff) + goffB[j]), \
                                   LP((dstbuf) + ((j) * 512 + t) * 8), 16, 0, 0)
#define LOAD_B(p) \
  { const short* bp = Bb + (p) * 8192 + bBase; \
    bf[0][0] = *(const frag8*)(bp + s0o); \
    bf[0][1] = *(const frag8*)(bp + s1o); \
    bf[1][0] = *(const frag8*)(bp + 1024 + s0o); \
    bf[1][1] = *(const frag8*)(bp + 1024 + s1o); }
#define MFMA_PH(p) \
  __builtin_amdgcn_s_barrier(); \
  asm volatile("s_waitcnt lgkmcnt(0)" ::: "memory"); \
  __builtin_amdgcn_s_setprio(1); \
  _Pragma("unroll") \
  for (int mf = 0; mf < 4; ++mf) { \
    acc[mf][2*(p)]   = __builtin_amdgcn_mfma_f32_16x16x32_bf16(af[mf][0], bf[0][0], acc[mf][2*(p)],   0, 0, 0); \
    acc[mf][2*(p)]   = __builtin_amdgcn_mfma_f32_16x16x32_bf16(af[mf][1], bf[0][1], acc[mf][2*(p)],   0, 0, 0); \
    acc[mf][2*(p)+1] = __builtin_amdgcn_mfma_f32_16x16x32_bf16(af[mf][0], bf[1][0], acc[mf][2*(p)+1], 0, 0, 0); \
    acc[mf][2*(p)+1] = __builtin_amdgcn_mfma_f32_16x16x32_bf16(af[mf][1], bf[1][1], acc[mf][2*(p)+1], 0, 0, 0); \
  } \
  __builtin_amdgcn_s_setprio(0);

  // ---- prologue: stage tile 0 (A0,A1,B00,B01,B10,B11); need A+B-unit0 -> vmcnt(2) ----
  STG_A(0, 0, &As[0][0]); STG_A(1, 0, &As[0][0]);
  STG_B(0, 0, &Bs[0][0]); STG_B(1, 0, &Bs[0][0]);
  STG_B(2, 0, &Bs[0][0]); STG_B(3, 0, &Bs[0][0]);
  asm volatile("s_waitcnt vmcnt(2)" ::: "memory");
  __builtin_amdgcn_s_barrier();

  for (int kt = 0; kt < 16; ++kt) {
    const short* Ab = As[kt & 1];
    const short* Bb = Bs[kt & 1];
    short* An = (short*)As[(kt & 1) ^ 1];
    short* Bn = (short*)Bs[(kt & 1) ^ 1];
    const int kn = (kt + 1) * 64;
    const bool pf = kt < 15;
    frag8 af[4][2], bf[2][2];

    // ---- phase 0: A frags (8 b128) + B unit 0 (4 b128); stage next A + B-unit0' ----
    #pragma unroll
    for (int mf = 0; mf < 4; ++mf) {
      const short* ap = Ab + aBase + mf * 1024;
      af[mf][0] = *(const frag8*)(ap + s0o);
      af[mf][1] = *(const frag8*)(ap + s1o);
    }
    LOAD_B(0);
    if (pf) { STG_A(0, kn, An); STG_A(1, kn, An); STG_B(0, kn, Bn); STG_B(1, kn, Bn); }
    MFMA_PH(0);
    if (pf) asm volatile("s_waitcnt vmcnt(4)" ::: "memory");  // B-unit1 landed (1.5 ph)
    else    asm volatile("s_waitcnt vmcnt(0)" ::: "memory");
    __builtin_amdgcn_s_barrier();

    // ---- phase 1: B unit 1 (4 b128); stage next B-unit1'; boundary wait ----
    LOAD_B(1);
    if (pf) { STG_B(2, kn, Bn); STG_B(3, kn, Bn); }
    MFMA_PH(1);
    if (pf) {  // next tile's A+B-unit0 landed (2-ph slack); B-unit1' stays in flight
      asm volatile("s_waitcnt vmcnt(2)" ::: "memory");
      __builtin_amdgcn_s_barrier();
    }
  }
#undef STG_A
#undef STG_B
#undef LOAD_B
#undef MFMA_PH

  // ---- epilogue: split into Q/K/V, Q scaled by QSC ----
  const int nb = n0 >> 10;                       // 256-tile never crosses 1024 boundary
  short* dst = nb == 0 ? Cq : (nb == 1 ? Ck : Cv);
  const float scl = (nb == 0) ? QSC : 1.0f;
  const int nl0 = (n0 & 1023) + wn * 64;
  const int rbase = m0 + wm * 64 + quad * 4;
  #pragma unroll
  for (int mf = 0; mf < 4; ++mf)
    #pragma unroll
    for (int nf = 0; nf < 4; ++nf)
      #pragma unroll
      for (int r = 0; r < 4; ++r) {
        int row = rbase + mf * 16 + r;
        int col = nl0 + nf * 16 + fm;
        dst[(size_t)row * 1024 + col] = f2bf(acc[mf][nf][r] * scl);
      }
}

// ------------- bf16 GEMM: C = A[MxK] * Bt[NxK]^T  (m97-style 128x128 tile) -------------
// MODE 1 only now: f32 output + bias (final projection; N=1024 -> 256^2 packs badly).
template <int MODE>
__global__ __launch_bounds__(256) void gemm_bt(const short* __restrict__ A,
                                               const short* __restrict__ Bt,
                                               void* __restrict__ C0,
                                               void* __restrict__ C1,
                                               void* __restrict__ C2,
                                               const float* __restrict__ bias,
                                               int M, int N, int K) {
  __shared__ short As[128 * 32];
  __shared__ short Bs[128 * 32];
  const int t = threadIdx.x;
  const int w = t >> 6, lane = t & 63;
  const int fm = lane & 15, quad = lane >> 4;
  const int m0 = blockIdx.y * 128, n0 = blockIdx.x * 128;
  const int wm = (w >> 1) * 64, wn = (w & 1) * 64;
  fx4 acc[4][4];
  #pragma unroll
  for (int i = 0; i < 4; ++i)
    #pragma unroll
    for (int j = 0; j < 4; ++j) acc[i][j] = (fx4){0.f, 0.f, 0.f, 0.f};

  for (int k0 = 0; k0 < K; k0 += 32) {
    #pragma unroll
    for (int i = 0; i < 2; ++i) {
      int chunk = i * 256 + t;            // 512 chunks of 16B per tile
      int row = chunk >> 2, cc = chunk & 3;
      __builtin_amdgcn_global_load_lds(GP(A + (size_t)(m0 + row) * K + k0 + cc * 8),
                                       LP(As + chunk * 8), 16, 0, 0);
      __builtin_amdgcn_global_load_lds(GP(Bt + (size_t)(n0 + row) * K + k0 + cc * 8),
                                       LP(Bs + chunk * 8), 16, 0, 0);
    }
    __syncthreads();
    frag8 af[4], bfr[4];
    #pragma unroll
    for (int mt = 0; mt < 4; ++mt)
      af[mt] = *(const frag8*)(As + (wm + mt * 16 + fm) * 32 + quad * 8);
    #pragma unroll
    for (int nt = 0; nt < 4; ++nt)
      bfr[nt] = *(const frag8*)(Bs + (wn + nt * 16 + fm) * 32 + quad * 8);
    #pragma unroll
    for (int mt = 0; mt < 4; ++mt)
      #pragma unroll
      for (int nt = 0; nt < 4; ++nt)
        acc[mt][nt] = __builtin_amdgcn_mfma_f32_16x16x32_bf16(af[mt], bfr[nt], acc[mt][nt], 0, 0, 0);
    __syncthreads();
  }
  #pragma unroll
  for (int mt = 0; mt < 4; ++mt)
    #pragma unroll
    for (int nt = 0; nt < 4; ++nt)
      #pragma unroll
      for (int r = 0; r < 4; ++r) {
        int row = m0 + wm + mt * 16 + quad * 4 + r;
        int col = n0 + wn + nt * 16 + fm;
        ((float*)C0)[(size_t)row * N + col] = acc[mt][nt][r] + bias[col];
      }
}

// ------------- attention v5: 64 q-rows per WAVE (256 per block), S^T trick -------------
// K/V tiles double-buffered; one __syncthreads per chunk (staging latency hidden under
// the previous chunk's QK^T+exp+PV compute).
__global__ __launch_bounds__(256, 2) void attn_kernel(const short* __restrict__ Q,
                                                      const short* __restrict__ K,
                                                      const short* __restrict__ Vt,
                                                      short* __restrict__ Ctx) {
  __shared__ short Ks[2][4096];       // 64 keys x 64 d, fragment-ordered (2 x 8 KB)
  __shared__ short Vs[2][4096];       // 64 d x 64 keys, fragment-ordered (2 x 8 KB)
  __shared__ short Plds[4 * 64 * 72]; // per-wave 64q x 64key, stride 72 (36 KB)
  const int bh = blockIdx.x, qt = blockIdx.y;
  const int t = threadIdx.x;
  const int w = t >> 6, lane = t & 63;
  const int fm = lane & 15, quad = lane >> 4;
  const short* Qb = Q + (size_t)bh * 65536;
  const short* Kb = K + (size_t)bh * 65536;
  const short* Vb = Vt + (size_t)bh * 65536;
  const int q0 = qt * 256 + w * 64;
  short* myP = Plds + w * 4608;

  frag8 qb[4][2];
  #pragma unroll
  for (int g = 0; g < 4; ++g)
    #pragma unroll
    for (int h = 0; h < 2; ++h)
      qb[g][h] = *(const frag8*)(Qb + (size_t)(q0 + g * 16 + fm) * 64 + h * 32 + quad * 8);

  fx4 O[4][4];
  #pragma unroll
  for (int g = 0; g < 4; ++g)
    #pragma unroll
    for (int nt = 0; nt < 4; ++nt) O[g][nt] = (fx4){0.f, 0.f, 0.f, 0.f};
  float lp[4] = {0.f, 0.f, 0.f, 0.f};

  int koff[2], voff[2], loff[2];
  #pragma unroll
  for (int i = 0; i < 2; ++i) {
    int c = i * 256 + t;
    int cf = c & 15, cq = (c >> 4) & 3, ch = (c >> 6) & 1, cg = c >> 7;
    koff[i] = (cg * 16 + cf) * 64 + ch * 32 + cq * 8;     // + key0*64
    voff[i] = (cg * 16 + cf) * 1024 + ch * 32 + cq * 8;   // + key0
    loff[i] = c * 8;
  }

  #pragma unroll
  for (int i = 0; i < 2; ++i) {
    __builtin_amdgcn_global_load_lds(GP(Kb + koff[i]), LP(&Ks[0][0] + loff[i]), 16, 0, 0);
    __builtin_amdgcn_global_load_lds(GP(Vb + voff[i]), LP(&Vs[0][0] + loff[i]), 16, 0, 0);
  }
  __syncthreads();

  for (int c = 0; c < 16; ++c) {
    const int cur = c & 1;
    if (c < 15) {
      const int key0n = (c + 1) * 64;
      #pragma unroll
      for (int i = 0; i < 2; ++i) {
        __builtin_amdgcn_global_load_lds(GP(Kb + (size_t)key0n * 64 + koff[i]),
                                         LP(&Ks[cur ^ 1][0] + loff[i]), 16, 0, 0);
        __builtin_amdgcn_global_load_lds(GP(Vb + (size_t)key0n + voff[i]),
                                         LP(&Vs[cur ^ 1][0] + loff[i]), 16, 0, 0);
      }
    }
    const short* Kc = &Ks[cur][0];
    const short* Vc = &Vs[cur][0];

    #pragma unroll
    for (int s = 0; s < 4; ++s) {
      frag8 k0 = *(const frag8*)(Kc + (s * 2 + 0) * 512 + lane * 8);
      frag8 k1 = *(const frag8*)(Kc + (s * 2 + 1) * 512 + lane * 8);
      #pragma unroll
      for (int g = 0; g < 4; ++g) {
        fx4 z = (fx4){0.f, 0.f, 0.f, 0.f};
        z = __builtin_amdgcn_mfma_f32_16x16x32_bf16(k0, qb[g][0], z, 0, 0, 0);
        z = __builtin_amdgcn_mfma_f32_16x16x32_bf16(k1, qb[g][1], z, 0, 0, 0);
        s4v pv;
        #pragma unroll
        for (int r = 0; r < 4; ++r) {
          float p = __builtin_amdgcn_exp2f(z[r]);
          lp[g] += p;
          union { float f; unsigned u; } cv; cv.f = p;
          pv[r] = (short)(cv.u >> 16);
        }
        *(s4v*)(myP + (g * 16 + fm) * 72 + s * 16 + quad * 4) = pv;
      }
    }
    asm volatile("s_waitcnt lgkmcnt(0)" ::: "memory");
    #pragma unroll
    for (int h = 0; h < 2; ++h) {
      frag8 pf[4];
      #pragma unroll
      for (int g = 0; g < 4; ++g)
        pf[g] = *(const frag8*)(myP + (g * 16 + fm) * 72 + h * 32 + quad * 8);
      #pragma unroll
      for (int nt = 0; nt < 4; ++nt) {
        frag8 vf = *(const frag8*)(Vc + (nt * 2 + h) * 512 + lane * 8);
        #pragma unroll
        for (int g = 0; g < 4; ++g)
          O[g][nt] = __builtin_amdgcn_mfma_f32_16x16x32_bf16(pf[g], vf, O[g][nt], 0, 0, 0);
      }
    }
    __syncthreads();
  }

  float rl[4][4];
  #pragma unroll
  for (int g = 0; g < 4; ++g) {
    float v = lp[g];
    v += __shfl_xor(v, 16, 64);
    v += __shfl_xor(v, 32, 64);
    float inv = 1.f / v;
    #pragma unroll
    for (int r = 0; r < 4; ++r) rl[g][r] = __shfl(inv, quad * 4 + r, 16);
  }
  const int b = bh >> 4, h = bh & 15;
  #pragma unroll
  for (int g = 0; g < 4; ++g)
    #pragma unroll
    for (int nt = 0; nt < 4; ++nt)
      #pragma unroll
      for (int r = 0; r < 4; ++r) {
        int row = b * 1024 + q0 + g * 16 + quad * 4 + r;  // gathered: [b*S+s][h*64+d]
        int col = h * 64 + nt * 16 + fm;
        Ctx[(size_t)row * 1024 + col] = f2bf(O[g][nt][r] * rl[g][r]);
      }
}

extern "C" void kernel_launch(void* const* d_in, const int* in_sizes, int n_in,
                              void* d_out, int out_size, void* d_ws, size_t ws_size,
                              hipStream_t stream) {
  const float* hs = (const float*)d_in[0];
  const float* wq = (const float*)d_in[1];
  const float* wk = (const float*)d_in[2];
  const float* wv = (const float*)d_in[3];
  const float* wo = (const float*)d_in[4];
  const float* bo = (const float*)d_in[5];
  float* out = (float*)d_out;

  char* wp = (char*)d_ws;
  const size_t MB16 = (size_t)Mm * Ee * 2;   // 16 MiB
  const size_t MB2  = (size_t)Ee * Ee * 2;   // 2 MiB
  short* Xb  = (short*)wp; wp += MB16;
  short* Wqt = (short*)wp; wp += MB2;   // Wqt/Wkt/Wvt/Wot contiguous = [4096][1024]
  short* Wkt = (short*)wp; wp += MB2;
  short* Wvt = (short*)wp; wp += MB2;
  short* Wot = (short*)wp; wp += MB2;
  short* Qb  = (short*)wp; wp += MB16;
  short* Kb  = (short*)wp; wp += MB16;
  short* Vb  = (short*)wp; wp += MB16;
  short* Vt  = (short*)wp; wp += MB16;
  short* Ctx = (short*)wp; wp += MB16;

  // 1. hidden -> bf16
  cvt_kernel<<<(Mm * Ee / 4 + 255) / 256, 256, 0, stream>>>(hs, Xb, Mm * Ee / 4);
  // 2. all 4 weights -> bf16 transposed [out][in], one launch
  transpose_cvt4<<<dim3(32, 32, 4), 256, 0, stream>>>(wq, wk, wv, wo, Wqt);
  // 3. fused QKV projection: 128x256-tile v2-style counted schedule, 768 blocks = 3 rounds
  gemm_qkv_8ph<<<768, 512, 0, stream>>>(Xb, Wqt, Qb, Kb, Vb);
  // 4. V -> Vt per head
  transpose_v<<<dim3(16, 128), 256, 0, stream>>>(Vb, Vt);
  // 5. attention -> gathered ctx (bf16); grid x=bh keeps same-bh blocks on one XCD
  attn_kernel<<<dim3(128, 4), 256, 0, stream>>>(Qb, Kb, Vt, Ctx);
  // 6. output projection + bias (fp32 out)
  gemm_bt<1><<<dim3(8, 64), 256, 0, stream>>>(Ctx, Wot, out, nullptr, nullptr, bo, Mm, Ee, Ee);
}

// Round 7
// 236.388 us; speedup vs baseline: 1.0760x; 1.0617x over previous
//
#include <hip/hip_runtime.h>
#include <hip/hip_bf16.h>
#include <stdint.h>
#include <stddef.h>

// ---- problem constants ----
static constexpr int Bb = 8, Ss = 1024, Ee = 1024, Hh = 16, Dd = 64;
static constexpr int Mm = Bb * Ss;            // 8192 rows
// per-(b,h) block of Q/K/V is contiguous [1024 x 64] at offset bh*65536 (reshape quirk)

typedef __attribute__((ext_vector_type(8))) short frag8;   // 8 x bf16 (4 VGPRs)
typedef __attribute__((ext_vector_type(4))) float fx4;     // 4 x f32 accumulator
typedef __attribute__((ext_vector_type(4))) short s4v;     // 4 x bf16 (8 B)

#define GP(p) ((const __attribute__((address_space(1))) void*)(p))
#define LP(p) ((__attribute__((address_space(3))) void*)(p))

static constexpr float QSC = 0.045084220027780106f;  // log2(e)/32: E^-0.5 + ln->log2, folded into Q

__device__ inline short f2bf(float x) {  // round-to-nearest-even fp32 -> bf16 bits
  union { float f; unsigned u; } c; c.f = x;
  unsigned u = c.u;
  unsigned r = (u + 0x7FFFu + ((u >> 16) & 1u)) >> 16;
  return (short)r;
}

// ---------------- fp32 -> bf16 elementwise (vectorized x4) ----------------
__global__ __launch_bounds__(256) void cvt_kernel(const float* __restrict__ in,
                                                  short* __restrict__ out, int n4) {
  int i = blockIdx.x * 256 + threadIdx.x;
  if (i >= n4) return;
  float4 v = *((const float4*)in + i);
  union { short s[4]; uint2 u; } o;
  o.s[0] = f2bf(v.x); o.s[1] = f2bf(v.y); o.s[2] = f2bf(v.z); o.s[3] = f2bf(v.w);
  *(uint2*)(out + (size_t)i * 4) = o.u;
}

// ------- transpose+convert 4 weights fp32 [K][N] -> bf16 [N][K] (z selects weight) -------
__global__ __launch_bounds__(256) void transpose_cvt4(const float* __restrict__ w0,
                                                      const float* __restrict__ w1,
                                                      const float* __restrict__ w2,
                                                      const float* __restrict__ w3,
                                                      short* __restrict__ WtBase) {
  __shared__ short tile[32][33];
  const int z = blockIdx.z;
  const float* W = z == 0 ? w0 : (z == 1 ? w1 : (z == 2 ? w2 : w3));
  short* Wt = WtBase + (size_t)z * 1024 * 1024;
  const int bx = blockIdx.x * 32;  // n
  const int by = blockIdx.y * 32;  // k
  const int tx = threadIdx.x & 31, ty = threadIdx.x >> 5;  // 32 x 8
  #pragma unroll
  for (int j = 0; j < 32; j += 8)
    tile[ty + j][tx] = f2bf(W[(size_t)(by + ty + j) * 1024 + bx + tx]);
  __syncthreads();
  #pragma unroll
  for (int j = 0; j < 32; j += 8)
    Wt[(size_t)(bx + ty + j) * 1024 + by + tx] = tile[tx][ty + j];
}

// ------------- per-head transpose V [bh][1024 s][64 d] -> Vt [bh][64 d][1024 s] -------------
__global__ __launch_bounds__(256) void transpose_v(const short* __restrict__ V,
                                                   short* __restrict__ Vt) {
  __shared__ short tile[64][65];
  const int bh = blockIdx.y;
  const int s0 = blockIdx.x * 64;
  const short* Vb = V + (size_t)bh * 65536;
  short* Vtb = Vt + (size_t)bh * 65536;
  const int tx = threadIdx.x & 63, ty = threadIdx.x >> 6;  // 64 x 4
  #pragma unroll
  for (int j = 0; j < 64; j += 4)
    tile[ty + j][tx] = Vb[(size_t)(s0 + ty + j) * 64 + tx];
  __syncthreads();
  #pragma unroll
  for (int j = 0; j < 64; j += 4)
    Vtb[(size_t)(ty + j) * 1024 + s0 + tx] = tile[tx][ty + j];
}

// ========== GEMM v5: 128x256 tile, BK=64, counted 2-phase schedule (r6-verified) ==========
// C = A[8192x1024] * Bt[NTILES*256 x 1024]^T.
// MODE 0 (NTILES=12): output split into Q/K/V bf16, Q scaled by QSC. 768 blocks = 3 rounds.
// MODE 1 (NTILES=4):  fp32 output + bias (final projection).      256 blocks = 1 round.
// 8 waves as 2M x 4N: per-wave C = 64x64 (4 m-frags x 4 n-frags, acc=64 VGPR).
// Per K-tile, 2 phases of 16 MFMA:
//   ph0: read A frags (8 b128) + B-unit0 (4 b128); stage next A (2) + B-unit0' (2)
//   ph1: read B-unit1 (4 b128);                    stage next B-unit1' (2)
// B LDS layout: unit u holds n-rows with (n>>5)&1==u, 128 rows each.
// LDS XOR-swizzle (chunk ^= row&7) on read + pre-swizzled global source (rule #21).
// Counted waits (FIFO-derived, wait-then-barrier; never 0 in steady loop):
//   end ph0 -> vmcnt(4)  [B-unit1 of CURRENT tile, issued 1.5 phases ago]
//   end ph1 -> vmcnt(2)  [next tile's A + B-unit0; leaves B-unit1' in flight]
// LDS = 2 x (16KB A + 32KB B) = 96KB -> 1 block/CU (8 waves).
template <int MODE, int NTILES>
__global__ __launch_bounds__(512, 2) void gemm_v5(const short* __restrict__ A,
                                                  const short* __restrict__ Bt,
                                                  void* __restrict__ C0,
                                                  void* __restrict__ C1,
                                                  void* __restrict__ C2,
                                                  const float* __restrict__ bias) {
  __shared__ short As[2][8192];    // [128 rows][64 shorts] linear, 16KB per buf
  __shared__ short Bs[2][16384];   // [2 units][128 rows][64 shorts], 32KB per buf
  const int t = threadIdx.x;
  const int w = t >> 6, lane = t & 63;
  const int fm = lane & 15, quad = lane >> 4;
  const int wm = w >> 2, wn = w & 3;            // 2M x 4N waves
  // XCD-aware swizzle: nwg = 64*NTILES, always %8==0 -> simple bijective form
  const int wg = (blockIdx.x & 7) * (8 * NTILES) + (blockIdx.x >> 3);
  const int nt_i = wg % NTILES, mt_i = wg / NTILES;  // consecutive wg share A-panel
  const int m0 = mt_i * 128, n0 = nt_i * 256;

  // ---- staging source offsets (pre-swizzled global; LDS dest is linear) ----
  int goffA[2], goffB[4];
  #pragma unroll
  for (int i = 0; i < 2; ++i) {
    int c = i * 512 + t, row = c >> 3, col8 = (c & 7) ^ (row & 7);
    goffA[i] = row * 1024 + col8 * 8;
  }
  #pragma unroll
  for (int j = 0; j < 4; ++j) {
    int u = j >> 1, i = j & 1;
    int c = i * 512 + t, r = c >> 3, col8 = (c & 7) ^ (r & 7);
    int n = (r >> 5) * 64 + u * 32 + (r & 31);
    goffB[j] = n * 1024 + col8 * 8;
  }
  const short* Ag = A + (size_t)m0 * 1024;
  const short* Bg = Bt + (size_t)n0 * 1024;

  fx4 acc[4][4];
  #pragma unroll
  for (int i = 0; i < 4; ++i)
    #pragma unroll
    for (int j = 0; j < 4; ++j) acc[i][j] = (fx4){0.f, 0.f, 0.f, 0.f};

  // ---- read-side constants (short offsets; chunk = 8 shorts) ----
  const int s0o = (quad ^ (fm & 7)) * 8;         // kk=0 swizzled chunk
  const int s1o = ((4 + quad) ^ (fm & 7)) * 8;   // kk=1
  const int aBase = (wm * 64 + fm) * 64;         // + mf*1024 + s?o
  const int bBase = (wn * 32 + fm) * 64;         // + p*8192 + e*1024 + s?o

#define STG_A(i, koff, dstbuf) \
  __builtin_amdgcn_global_load_lds(GP(Ag + (koff) + goffA[i]), \
                                   LP((dstbuf) + ((i) * 512 + t) * 8), 16, 0, 0)
#define STG_B(j, koff, dstbuf) \
  __builtin_amdgcn_global_load_lds(GP(Bg + (koff) + goffB[j]), \
                                   LP((dstbuf) + ((j) * 512 + t) * 8), 16, 0, 0)
#define LOAD_B(p) \
  { const short* bp = Bb + (p) * 8192 + bBase; \
    bf[0][0] = *(const frag8*)(bp + s0o); \
    bf[0][1] = *(const frag8*)(bp + s1o); \
    bf[1][0] = *(const frag8*)(bp + 1024 + s0o); \
    bf[1][1] = *(const frag8*)(bp + 1024 + s1o); }
#define MFMA_PH(p) \
  __builtin_amdgcn_s_barrier(); \
  asm volatile("s_waitcnt lgkmcnt(0)" ::: "memory"); \
  __builtin_amdgcn_s_setprio(1); \
  _Pragma("unroll") \
  for (int mf = 0; mf < 4; ++mf) { \
    acc[mf][2*(p)]   = __builtin_amdgcn_mfma_f32_16x16x32_bf16(af[mf][0], bf[0][0], acc[mf][2*(p)],   0, 0, 0); \
    acc[mf][2*(p)]   = __builtin_amdgcn_mfma_f32_16x16x32_bf16(af[mf][1], bf[0][1], acc[mf][2*(p)],   0, 0, 0); \
    acc[mf][2*(p)+1] = __builtin_amdgcn_mfma_f32_16x16x32_bf16(af[mf][0], bf[1][0], acc[mf][2*(p)+1], 0, 0, 0); \
    acc[mf][2*(p)+1] = __builtin_amdgcn_mfma_f32_16x16x32_bf16(af[mf][1], bf[1][1], acc[mf][2*(p)+1], 0, 0, 0); \
  } \
  __builtin_amdgcn_s_setprio(0);

  // ---- prologue: stage tile 0; need A + B-unit0 -> vmcnt(2) ----
  STG_A(0, 0, &As[0][0]); STG_A(1, 0, &As[0][0]);
  STG_B(0, 0, &Bs[0][0]); STG_B(1, 0, &Bs[0][0]);
  STG_B(2, 0, &Bs[0][0]); STG_B(3, 0, &Bs[0][0]);
  asm volatile("s_waitcnt vmcnt(2)" ::: "memory");
  __builtin_amdgcn_s_barrier();

  for (int kt = 0; kt < 16; ++kt) {
    const short* Ab = As[kt & 1];
    const short* Bb = Bs[kt & 1];
    short* An = (short*)As[(kt & 1) ^ 1];
    short* Bn = (short*)Bs[(kt & 1) ^ 1];
    const int kn = (kt + 1) * 64;
    const bool pf = kt < 15;
    frag8 af[4][2], bf[2][2];

    // ---- phase 0: A frags (8 b128) + B unit 0 (4 b128); stage next A + B-unit0' ----
    #pragma unroll
    for (int mf = 0; mf < 4; ++mf) {
      const short* ap = Ab + aBase + mf * 1024;
      af[mf][0] = *(const frag8*)(ap + s0o);
      af[mf][1] = *(const frag8*)(ap + s1o);
    }
    LOAD_B(0);
    if (pf) { STG_A(0, kn, An); STG_A(1, kn, An); STG_B(0, kn, Bn); STG_B(1, kn, Bn); }
    MFMA_PH(0);
    if (pf) asm volatile("s_waitcnt vmcnt(4)" ::: "memory");  // B-unit1 landed (1.5 ph)
    else    asm volatile("s_waitcnt vmcnt(0)" ::: "memory");
    __builtin_amdgcn_s_barrier();

    // ---- phase 1: B unit 1 (4 b128); stage next B-unit1'; boundary wait ----
    LOAD_B(1);
    if (pf) { STG_B(2, kn, Bn); STG_B(3, kn, Bn); }
    MFMA_PH(1);
    if (pf) {  // next tile's A+B-unit0 landed (2-ph slack); B-unit1' stays in flight
      asm volatile("s_waitcnt vmcnt(2)" ::: "memory");
      __builtin_amdgcn_s_barrier();
    }
  }
#undef STG_A
#undef STG_B
#undef LOAD_B
#undef MFMA_PH

  const int rbase = m0 + wm * 64 + quad * 4;
  if (MODE == 0) {
    // ---- epilogue: split into Q/K/V bf16, Q scaled by QSC ----
    const int nb = n0 >> 10;                     // 256-tile never crosses 1024 boundary
    short* dst = nb == 0 ? (short*)C0 : (nb == 1 ? (short*)C1 : (short*)C2);
    const float scl = (nb == 0) ? QSC : 1.0f;
    const int nl0 = (n0 & 1023) + wn * 64;
    #pragma unroll
    for (int mf = 0; mf < 4; ++mf)
      #pragma unroll
      for (int nf = 0; nf < 4; ++nf)
        #pragma unroll
        for (int r = 0; r < 4; ++r) {
          int row = rbase + mf * 16 + r;
          int col = nl0 + nf * 16 + fm;
          dst[(size_t)row * 1024 + col] = f2bf(acc[mf][nf][r] * scl);
        }
  } else {
    // ---- epilogue: fp32 + bias (out-projection) ----
    float* dst = (float*)C0;
    const int nl0 = n0 + wn * 64;
    #pragma unroll
    for (int mf = 0; mf < 4; ++mf)
      #pragma unroll
      for (int nf = 0; nf < 4; ++nf) {
        const float bv = bias[nl0 + nf * 16 + fm];
        #pragma unroll
        for (int r = 0; r < 4; ++r) {
          int row = rbase + mf * 16 + r;
          int col = nl0 + nf * 16 + fm;
          dst[(size_t)row * 1024 + col] = acc[mf][nf][r] + bv;
        }
      }
  }
}

// ------------- attention v5: 64 q-rows per WAVE (256 per block), S^T trick -------------
// K/V tiles double-buffered; one __syncthreads per chunk (staging latency hidden under
// the previous chunk's QK^T+exp+PV compute).
__global__ __launch_bounds__(256, 2) void attn_kernel(const short* __restrict__ Q,
                                                      const short* __restrict__ K,
                                                      const short* __restrict__ Vt,
                                                      short* __restrict__ Ctx) {
  __shared__ short Ks[2][4096];       // 64 keys x 64 d, fragment-ordered (2 x 8 KB)
  __shared__ short Vs[2][4096];       // 64 d x 64 keys, fragment-ordered (2 x 8 KB)
  __shared__ short Plds[4 * 64 * 72]; // per-wave 64q x 64key, stride 72 (36 KB)
  const int bh = blockIdx.x, qt = blockIdx.y;
  const int t = threadIdx.x;
  const int w = t >> 6, lane = t & 63;
  const int fm = lane & 15, quad = lane >> 4;
  const short* Qb = Q + (size_t)bh * 65536;
  const short* Kb = K + (size_t)bh * 65536;
  const short* Vb = Vt + (size_t)bh * 65536;
  const int q0 = qt * 256 + w * 64;
  short* myP = Plds + w * 4608;

  frag8 qb[4][2];
  #pragma unroll
  for (int g = 0; g < 4; ++g)
    #pragma unroll
    for (int h = 0; h < 2; ++h)
      qb[g][h] = *(const frag8*)(Qb + (size_t)(q0 + g * 16 + fm) * 64 + h * 32 + quad * 8);

  fx4 O[4][4];
  #pragma unroll
  for (int g = 0; g < 4; ++g)
    #pragma unroll
    for (int nt = 0; nt < 4; ++nt) O[g][nt] = (fx4){0.f, 0.f, 0.f, 0.f};
  float lp[4] = {0.f, 0.f, 0.f, 0.f};

  int koff[2], voff[2], loff[2];
  #pragma unroll
  for (int i = 0; i < 2; ++i) {
    int c = i * 256 + t;
    int cf = c & 15, cq = (c >> 4) & 3, ch = (c >> 6) & 1, cg = c >> 7;
    koff[i] = (cg * 16 + cf) * 64 + ch * 32 + cq * 8;     // + key0*64
    voff[i] = (cg * 16 + cf) * 1024 + ch * 32 + cq * 8;   // + key0
    loff[i] = c * 8;
  }

  #pragma unroll
  for (int i = 0; i < 2; ++i) {
    __builtin_amdgcn_global_load_lds(GP(Kb + koff[i]), LP(&Ks[0][0] + loff[i]), 16, 0, 0);
    __builtin_amdgcn_global_load_lds(GP(Vb + voff[i]), LP(&Vs[0][0] + loff[i]), 16, 0, 0);
  }
  __syncthreads();

  for (int c = 0; c < 16; ++c) {
    const int cur = c & 1;
    if (c < 15) {
      const int key0n = (c + 1) * 64;
      #pragma unroll
      for (int i = 0; i < 2; ++i) {
        __builtin_amdgcn_global_load_lds(GP(Kb + (size_t)key0n * 64 + koff[i]),
                                         LP(&Ks[cur ^ 1][0] + loff[i]), 16, 0, 0);
        __builtin_amdgcn_global_load_lds(GP(Vb + (size_t)key0n + voff[i]),
                                         LP(&Vs[cur ^ 1][0] + loff[i]), 16, 0, 0);
      }
    }
    const short* Kc = &Ks[cur][0];
    const short* Vc = &Vs[cur][0];

    #pragma unroll
    for (int s = 0; s < 4; ++s) {
      frag8 k0 = *(const frag8*)(Kc + (s * 2 + 0) * 512 + lane * 8);
      frag8 k1 = *(const frag8*)(Kc + (s * 2 + 1) * 512 + lane * 8);
      #pragma unroll
      for (int g = 0; g < 4; ++g) {
        fx4 z = (fx4){0.f, 0.f, 0.f, 0.f};
        z = __builtin_amdgcn_mfma_f32_16x16x32_bf16(k0, qb[g][0], z, 0, 0, 0);
        z = __builtin_amdgcn_mfma_f32_16x16x32_bf16(k1, qb[g][1], z, 0, 0, 0);
        s4v pv;
        #pragma unroll
        for (int r = 0; r < 4; ++r) {
          float p = __builtin_amdgcn_exp2f(z[r]);
          lp[g] += p;
          union { float f; unsigned u; } cv; cv.f = p;
          pv[r] = (short)(cv.u >> 16);
        }
        *(s4v*)(myP + (g * 16 + fm) * 72 + s * 16 + quad * 4) = pv;
      }
    }
    asm volatile("s_waitcnt lgkmcnt(0)" ::: "memory");
    #pragma unroll
    for (int h = 0; h < 2; ++h) {
      frag8 pf[4];
      #pragma unroll
      for (int g = 0; g < 4; ++g)
        pf[g] = *(const frag8*)(myP + (g * 16 + fm) * 72 + h * 32 + quad * 8);
      #pragma unroll
      for (int nt = 0; nt < 4; ++nt) {
        frag8 vf = *(const frag8*)(Vc + (nt * 2 + h) * 512 + lane * 8);
        #pragma unroll
        for (int g = 0; g < 4; ++g)
          O[g][nt] = __builtin_amdgcn_mfma_f32_16x16x32_bf16(pf[g], vf, O[g][nt], 0, 0, 0);
      }
    }
    __syncthreads();
  }

  float rl[4][4];
  #pragma unroll
  for (int g = 0; g < 4; ++g) {
    float v = lp[g];
    v += __shfl_xor(v, 16, 64);
    v += __shfl_xor(v, 32, 64);
    float inv = 1.f / v;
    #pragma unroll
    for (int r = 0; r < 4; ++r) rl[g][r] = __shfl(inv, quad * 4 + r, 16);
  }
  const int b = bh >> 4, h = bh & 15;
  #pragma unroll
  for (int g = 0; g < 4; ++g)
    #pragma unroll
    for (int nt = 0; nt < 4; ++nt)
      #pragma unroll
      for (int r = 0; r < 4; ++r) {
        int row = b * 1024 + q0 + g * 16 + quad * 4 + r;  // gathered: [b*S+s][h*64+d]
        int col = h * 64 + nt * 16 + fm;
        Ctx[(size_t)row * 1024 + col] = f2bf(O[g][nt][r] * rl[g][r]);
      }
}

extern "C" void kernel_launch(void* const* d_in, const int* in_sizes, int n_in,
                              void* d_out, int out_size, void* d_ws, size_t ws_size,
                              hipStream_t stream) {
  const float* hs = (const float*)d_in[0];
  const float* wq = (const float*)d_in[1];
  const float* wk = (const float*)d_in[2];
  const float* wv = (const float*)d_in[3];
  const float* wo = (const float*)d_in[4];
  const float* bo = (const float*)d_in[5];
  float* out = (float*)d_out;

  char* wp = (char*)d_ws;
  const size_t MB16 = (size_t)Mm * Ee * 2;   // 16 MiB
  const size_t MB2  = (size_t)Ee * Ee * 2;   // 2 MiB
  short* Xb  = (short*)wp; wp += MB16;
  short* Wqt = (short*)wp; wp += MB2;   // Wqt/Wkt/Wvt/Wot contiguous = [4096][1024]
  short* Wkt = (short*)wp; wp += MB2;
  short* Wvt = (short*)wp; wp += MB2;
  short* Wot = (short*)wp; wp += MB2;
  short* Qb  = (short*)wp; wp += MB16;
  short* Kb  = (short*)wp; wp += MB16;
  short* Vb  = (short*)wp; wp += MB16;
  short* Vt  = (short*)wp; wp += MB16;
  short* Ctx = (short*)wp; wp += MB16;

  // 1. hidden -> bf16
  cvt_kernel<<<(Mm * Ee / 4 + 255) / 256, 256, 0, stream>>>(hs, Xb, Mm * Ee / 4);
  // 2. all 4 weights -> bf16 transposed [out][in], one launch
  transpose_cvt4<<<dim3(32, 32, 4), 256, 0, stream>>>(wq, wk, wv, wo, Wqt);
  // 3. fused QKV projection: 128x256-tile counted schedule, 768 blocks = 3 rounds
  gemm_v5<0, 12><<<768, 512, 0, stream>>>(Xb, Wqt, Qb, Kb, Vb, nullptr);
  // 4. V -> Vt per head
  transpose_v<<<dim3(16, 128), 256, 0, stream>>>(Vb, Vt);
  // 5. attention -> gathered ctx (bf16); grid x=bh keeps same-bh blocks on one XCD
  attn_kernel<<<dim3(128, 4), 256, 0, stream>>>(Qb, Kb, Vt, Ctx);
  // 6. output projection + bias: SAME v5 structure, 256 blocks = exactly 1 round
  gemm_v5<1, 4><<<256, 512, 0, stream>>>(Ctx, Wot, out, nullptr, nullptr, bo);
}

// Round 9
// 230.831 us; speedup vs baseline: 1.1019x; 1.0241x over previous
//
#include <hip/hip_runtime.h>
#include <hip/hip_bf16.h>
#include <stdint.h>
#include <stddef.h>

// ---- problem constants ----
static constexpr int Bb = 8, Ss = 1024, Ee = 1024, Hh = 16, Dd = 64;
static constexpr int Mm = Bb * Ss;            // 8192 rows
// per-(b,h) block of Q/K/V is contiguous [1024 x 64] at offset bh*65536 (reshape quirk).
// NOTE (r8 lesson): the quirk maps GEMM-output (row,col) -> b=row>>10, h=(row>>6)&15,
// s'=(row&63)*16+(col>>6), d=col&63 — h comes from ROW bits. A fused "transposed V"
// epilogue under this mapping degenerates to 2B scattered stores (4x sector
// amplification > transpose_v's 48MB round trip), so V keeps the dedicated transpose.

typedef __attribute__((ext_vector_type(8))) short frag8;   // 8 x bf16 (4 VGPRs)
typedef __attribute__((ext_vector_type(4))) float fx4;     // 4 x f32 accumulator
typedef __attribute__((ext_vector_type(4))) short s4v;     // 4 x bf16 (8 B)

#define GP(p) ((const __attribute__((address_space(1))) void*)(p))
#define LP(p) ((__attribute__((address_space(3))) void*)(p))

static constexpr float QSC = 0.045084220027780106f;  // log2(e)/32: E^-0.5 + ln->log2, folded into Q

__device__ inline short f2bf(float x) {  // round-to-nearest-even fp32 -> bf16 bits
  union { float f; unsigned u; } c; c.f = x;
  unsigned u = c.u;
  unsigned r = (u + 0x7FFFu + ((u >> 16) & 1u)) >> 16;
  return (short)r;
}

// ---------------- fp32 -> bf16 elementwise (vectorized x4) ----------------
__global__ __launch_bounds__(256) void cvt_kernel(const float* __restrict__ in,
                                                  short* __restrict__ out, int n4) {
  int i = blockIdx.x * 256 + threadIdx.x;
  if (i >= n4) return;
  float4 v = *((const float4*)in + i);
  union { short s[4]; uint2 u; } o;
  o.s[0] = f2bf(v.x); o.s[1] = f2bf(v.y); o.s[2] = f2bf(v.z); o.s[3] = f2bf(v.w);
  *(uint2*)(out + (size_t)i * 4) = o.u;
}

// ------- transpose+convert 4 weights fp32 [K][N] -> bf16 [N][K] (z selects weight) -------
__global__ __launch_bounds__(256) void transpose_cvt4(const float* __restrict__ w0,
                                                      const float* __restrict__ w1,
                                                      const float* __restrict__ w2,
                                                      const float* __restrict__ w3,
                                                      short* __restrict__ WtBase) {
  __shared__ short tile[32][33];
  const int z = blockIdx.z;
  const float* W = z == 0 ? w0 : (z == 1 ? w1 : (z == 2 ? w2 : w3));
  short* Wt = WtBase + (size_t)z * 1024 * 1024;
  const int bx = blockIdx.x * 32;  // n
  const int by = blockIdx.y * 32;  // k
  const int tx = threadIdx.x & 31, ty = threadIdx.x >> 5;  // 32 x 8
  #pragma unroll
  for (int j = 0; j < 32; j += 8)
    tile[ty + j][tx] = f2bf(W[(size_t)(by + ty + j) * 1024 + bx + tx]);
  __syncthreads();
  #pragma unroll
  for (int j = 0; j < 32; j += 8)
    Wt[(size_t)(bx + ty + j) * 1024 + by + tx] = tile[tx][ty + j];
}

// ------------- per-head transpose V [bh][1024 s][64 d] -> Vt [bh][64 d][1024 s] -------------
__global__ __launch_bounds__(256) void transpose_v(const short* __restrict__ V,
                                                   short* __restrict__ Vt) {
  __shared__ short tile[64][65];
  const int bh = blockIdx.y;
  const int s0 = blockIdx.x * 64;
  const short* Vb = V + (size_t)bh * 65536;
  short* Vtb = Vt + (size_t)bh * 65536;
  const int tx = threadIdx.x & 63, ty = threadIdx.x >> 6;  // 64 x 4
  #pragma unroll
  for (int j = 0; j < 64; j += 4)
    tile[ty + j][tx] = Vb[(size_t)(s0 + ty + j) * 64 + tx];
  __syncthreads();
  #pragma unroll
  for (int j = 0; j < 64; j += 4)
    Vtb[(size_t)(ty + j) * 1024 + s0 + tx] = tile[tx][ty + j];
}

// ========== GEMM v5: 128x256 tile, BK=64, counted 2-phase schedule (r6/r7-verified) ==========
// C = A[8192x1024] * Bt[NTILES*256 x 1024]^T.
// MODE 0 (NTILES=12): Q/K/V bf16 row-major split, Q scaled by QSC. 768 blocks = 3 rounds.
// MODE 1 (NTILES=4):  fp32 output + bias (final projection).      256 blocks = 1 round.
// 8 waves as 2M x 4N: per-wave C = 64x64 (4 m-frags x 4 n-frags, acc=64 VGPR).
// Per K-tile, 2 phases of 16 MFMA:
//   ph0: read A frags (8 b128) + B-unit0 (4 b128); stage next A (2) + B-unit0' (2)
//   ph1: read B-unit1 (4 b128);                    stage next B-unit1' (2)
// B LDS layout: unit u holds n-rows with (n>>5)&1==u, 128 rows each.
// LDS XOR-swizzle (chunk ^= row&7) on read + pre-swizzled global source (rule #21).
// Counted waits (FIFO-derived, wait-then-barrier; never 0 in steady loop):
//   end ph0 -> vmcnt(4)  [B-unit1 of CURRENT tile, issued 1.5 phases ago]
//   end ph1 -> vmcnt(2)  [next tile's A + B-unit0; leaves B-unit1' in flight]
// LDS = 2 x (16KB A + 32KB B) = 96KB -> 1 block/CU (8 waves).
template <int MODE, int NTILES>
__global__ __launch_bounds__(512, 2) void gemm_v5(const short* __restrict__ A,
                                                  const short* __restrict__ Bt,
                                                  void* __restrict__ C0,
                                                  void* __restrict__ C1,
                                                  void* __restrict__ C2,
                                                  const float* __restrict__ bias) {
  __shared__ short As[2][8192];    // [128 rows][64 shorts] linear, 16KB per buf
  __shared__ short Bs[2][16384];   // [2 units][128 rows][64 shorts], 32KB per buf
  const int t = threadIdx.x;
  const int w = t >> 6, lane = t & 63;
  const int fm = lane & 15, quad = lane >> 4;
  const int wm = w >> 2, wn = w & 3;            // 2M x 4N waves
  // XCD-aware swizzle: nwg = 64*NTILES, always %8==0 -> simple bijective form
  const int wg = (blockIdx.x & 7) * (8 * NTILES) + (blockIdx.x >> 3);
  const int nt_i = wg % NTILES, mt_i = wg / NTILES;  // consecutive wg share A-panel
  const int m0 = mt_i * 128, n0 = nt_i * 256;

  // ---- staging source offsets (pre-swizzled global; LDS dest is linear) ----
  int goffA[2], goffB[4];
  #pragma unroll
  for (int i = 0; i < 2; ++i) {
    int c = i * 512 + t, row = c >> 3, col8 = (c & 7) ^ (row & 7);
    goffA[i] = row * 1024 + col8 * 8;
  }
  #pragma unroll
  for (int j = 0; j < 4; ++j) {
    int u = j >> 1, i = j & 1;
    int c = i * 512 + t, r = c >> 3, col8 = (c & 7) ^ (r & 7);
    int n = (r >> 5) * 64 + u * 32 + (r & 31);
    goffB[j] = n * 1024 + col8 * 8;
  }
  const short* Ag = A + (size_t)m0 * 1024;
  const short* Bg = Bt + (size_t)n0 * 1024;

  fx4 acc[4][4];
  #pragma unroll
  for (int i = 0; i < 4; ++i)
    #pragma unroll
    for (int j = 0; j < 4; ++j) acc[i][j] = (fx4){0.f, 0.f, 0.f, 0.f};

  // ---- read-side constants (short offsets; chunk = 8 shorts) ----
  const int s0o = (quad ^ (fm & 7)) * 8;         // kk=0 swizzled chunk
  const int s1o = ((4 + quad) ^ (fm & 7)) * 8;   // kk=1
  const int aBase = (wm * 64 + fm) * 64;         // + mf*1024 + s?o
  const int bBase = (wn * 32 + fm) * 64;         // + p*8192 + e*1024 + s?o

#define STG_A(i, koff, dstbuf) \
  __builtin_amdgcn_global_load_lds(GP(Ag + (koff) + goffA[i]), \
                                   LP((dstbuf) + ((i) * 512 + t) * 8), 16, 0, 0)
#define STG_B(j, koff, dstbuf) \
  __builtin_amdgcn_global_load_lds(GP(Bg + (koff) + goffB[j]), \
                                   LP((dstbuf) + ((j) * 512 + t) * 8), 16, 0, 0)
#define LOAD_B(p) \
  { const short* bp = Bb + (p) * 8192 + bBase; \
    bf[0][0] = *(const frag8*)(bp + s0o); \
    bf[0][1] = *(const frag8*)(bp + s1o); \
    bf[1][0] = *(const frag8*)(bp + 1024 + s0o); \
    bf[1][1] = *(const frag8*)(bp + 1024 + s1o); }
#define MFMA_PH(p) \
  __builtin_amdgcn_s_barrier(); \
  asm volatile("s_waitcnt lgkmcnt(0)" ::: "memory"); \
  __builtin_amdgcn_s_setprio(1); \
  _Pragma("unroll") \
  for (int mf = 0; mf < 4; ++mf) { \
    acc[mf][2*(p)]   = __builtin_amdgcn_mfma_f32_16x16x32_bf16(af[mf][0], bf[0][0], acc[mf][2*(p)],   0, 0, 0); \
    acc[mf][2*(p)]   = __builtin_amdgcn_mfma_f32_16x16x32_bf16(af[mf][1], bf[0][1], acc[mf][2*(p)],   0, 0, 0); \
    acc[mf][2*(p)+1] = __builtin_amdgcn_mfma_f32_16x16x32_bf16(af[mf][0], bf[1][0], acc[mf][2*(p)+1], 0, 0, 0); \
    acc[mf][2*(p)+1] = __builtin_amdgcn_mfma_f32_16x16x32_bf16(af[mf][1], bf[1][1], acc[mf][2*(p)+1], 0, 0, 0); \
  } \
  __builtin_amdgcn_s_setprio(0);

  // ---- prologue: stage tile 0; need A + B-unit0 -> vmcnt(2) ----
  STG_A(0, 0, &As[0][0]); STG_A(1, 0, &As[0][0]);
  STG_B(0, 0, &Bs[0][0]); STG_B(1, 0, &Bs[0][0]);
  STG_B(2, 0, &Bs[0][0]); STG_B(3, 0, &Bs[0][0]);
  asm volatile("s_waitcnt vmcnt(2)" ::: "memory");
  __builtin_amdgcn_s_barrier();

  for (int kt = 0; kt < 16; ++kt) {
    const short* Ab = As[kt & 1];
    const short* Bb = Bs[kt & 1];
    short* An = (short*)As[(kt & 1) ^ 1];
    short* Bn = (short*)Bs[(kt & 1) ^ 1];
    const int kn = (kt + 1) * 64;
    const bool pf = kt < 15;
    frag8 af[4][2], bf[2][2];

    // ---- phase 0: A frags (8 b128) + B unit 0 (4 b128); stage next A + B-unit0' ----
    #pragma unroll
    for (int mf = 0; mf < 4; ++mf) {
      const short* ap = Ab + aBase + mf * 1024;
      af[mf][0] = *(const frag8*)(ap + s0o);
      af[mf][1] = *(const frag8*)(ap + s1o);
    }
    LOAD_B(0);
    if (pf) { STG_A(0, kn, An); STG_A(1, kn, An); STG_B(0, kn, Bn); STG_B(1, kn, Bn); }
    MFMA_PH(0);
    if (pf) asm volatile("s_waitcnt vmcnt(4)" ::: "memory");  // B-unit1 landed (1.5 ph)
    else    asm volatile("s_waitcnt vmcnt(0)" ::: "memory");
    __builtin_amdgcn_s_barrier();

    // ---- phase 1: B unit 1 (4 b128); stage next B-unit1'; boundary wait ----
    LOAD_B(1);
    if (pf) { STG_B(2, kn, Bn); STG_B(3, kn, Bn); }
    MFMA_PH(1);
    if (pf) {  // next tile's A+B-unit0 landed (2-ph slack); B-unit1' stays in flight
      asm volatile("s_waitcnt vmcnt(2)" ::: "memory");
      __builtin_amdgcn_s_barrier();
    }
  }
#undef STG_A
#undef STG_B
#undef LOAD_B
#undef MFMA_PH

  const int rbase = m0 + wm * 64 + quad * 4;
  if (MODE == 0) {
    // ---- epilogue: split into Q/K/V bf16 row-major, Q scaled by QSC ----
    const int nb = n0 >> 10;                     // 256-tile never crosses 1024 boundary
    short* dst = nb == 0 ? (short*)C0 : (nb == 1 ? (short*)C1 : (short*)C2);
    const float scl = (nb == 0) ? QSC : 1.0f;
    const int nl0 = (n0 & 1023) + wn * 64;
    #pragma unroll
    for (int mf = 0; mf < 4; ++mf)
      #pragma unroll
      for (int nf = 0; nf < 4; ++nf)
        #pragma unroll
        for (int r = 0; r < 4; ++r) {
          int row = rbase + mf * 16 + r;
          int col = nl0 + nf * 16 + fm;
          dst[(size_t)row * 1024 + col] = f2bf(acc[mf][nf][r] * scl);
        }
  } else {
    // ---- epilogue: fp32 + bias (out-projection) ----
    float* dst = (float*)C0;
    const int nl0 = n0 + wn * 64;
    #pragma unroll
    for (int mf = 0; mf < 4; ++mf)
      #pragma unroll
      for (int nf = 0; nf < 4; ++nf) {
        const float bv = bias[nl0 + nf * 16 + fm];
        #pragma unroll
        for (int r = 0; r < 4; ++r) {
          int row = rbase + mf * 16 + r;
          int col = nl0 + nf * 16 + fm;
          dst[(size_t)row * 1024 + col] = acc[mf][nf][r] + bv;
        }
      }
  }
}

// ------------- attention v6: 64 q-rows per WAVE (256 per block), S^T trick -------------
// K/V tiles double-buffered; one __syncthreads per chunk. r9: ONLY change vs r7 is
// min-waves 2 -> 3 (LDS 52KB x3 = 156 <= 160; VGPR capped ~168) for +50% TLP on the
// long MFMA->exp2->ds_write->lgkm->ds_read->MFMA chain.
__global__ __launch_bounds__(256, 3) void attn_kernel(const short* __restrict__ Q,
                                                      const short* __restrict__ K,
                                                      const short* __restrict__ Vt,
                                                      short* __restrict__ Ctx) {
  __shared__ short Ks[2][4096];       // 64 keys x 64 d, fragment-ordered (2 x 8 KB)
  __shared__ short Vs[2][4096];       // 64 d x 64 keys, fragment-ordered (2 x 8 KB)
  __shared__ short Plds[4 * 64 * 72]; // per-wave 64q x 64key, stride 72 (36 KB)
  const int bh = blockIdx.x, qt = blockIdx.y;
  const int t = threadIdx.x;
  const int w = t >> 6, lane = t & 63;
  const int fm = lane & 15, quad = lane >> 4;
  const short* Qb = Q + (size_t)bh * 65536;
  const short* Kb = K + (size_t)bh * 65536;
  const short* Vb = Vt + (size_t)bh * 65536;
  const int q0 = qt * 256 + w * 64;
  short* myP = Plds + w * 4608;

  frag8 qb[4][2];
  #pragma unroll
  for (int g = 0; g < 4; ++g)
    #pragma unroll
    for (int h = 0; h < 2; ++h)
      qb[g][h] = *(const frag8*)(Qb + (size_t)(q0 + g * 16 + fm) * 64 + h * 32 + quad * 8);

  fx4 O[4][4];
  #pragma unroll
  for (int g = 0; g < 4; ++g)
    #pragma unroll
    for (int nt = 0; nt < 4; ++nt) O[g][nt] = (fx4){0.f, 0.f, 0.f, 0.f};
  float lp[4] = {0.f, 0.f, 0.f, 0.f};

  int koff[2], voff[2], loff[2];
  #pragma unroll
  for (int i = 0; i < 2; ++i) {
    int c = i * 256 + t;
    int cf = c & 15, cq = (c >> 4) & 3, ch = (c >> 6) & 1, cg = c >> 7;
    koff[i] = (cg * 16 + cf) * 64 + ch * 32 + cq * 8;     // + key0*64
    voff[i] = (cg * 16 + cf) * 1024 + ch * 32 + cq * 8;   // + key0
    loff[i] = c * 8;
  }

  #pragma unroll
  for (int i = 0; i < 2; ++i) {
    __builtin_amdgcn_global_load_lds(GP(Kb + koff[i]), LP(&Ks[0][0] + loff[i]), 16, 0, 0);
    __builtin_amdgcn_global_load_lds(GP(Vb + voff[i]), LP(&Vs[0][0] + loff[i]), 16, 0, 0);
  }
  __syncthreads();

  for (int c = 0; c < 16; ++c) {
    const int cur = c & 1;
    if (c < 15) {
      const int key0n = (c + 1) * 64;
      #pragma unroll
      for (int i = 0; i < 2; ++i) {
        __builtin_amdgcn_global_load_lds(GP(Kb + (size_t)key0n * 64 + koff[i]),
                                         LP(&Ks[cur ^ 1][0] + loff[i]), 16, 0, 0);
        __builtin_amdgcn_global_load_lds(GP(Vb + (size_t)key0n + voff[i]),
                                         LP(&Vs[cur ^ 1][0] + loff[i]), 16, 0, 0);
      }
    }
    const short* Kc = &Ks[cur][0];
    const short* Vc = &Vs[cur][0];

    #pragma unroll
    for (int s = 0; s < 4; ++s) {
      frag8 k0 = *(const frag8*)(Kc + (s * 2 + 0) * 512 + lane * 8);
      frag8 k1 = *(const frag8*)(Kc + (s * 2 + 1) * 512 + lane * 8);
      #pragma unroll
      for (int g = 0; g < 4; ++g) {
        fx4 z = (fx4){0.f, 0.f, 0.f, 0.f};
        z = __builtin_amdgcn_mfma_f32_16x16x32_bf16(k0, qb[g][0], z, 0, 0, 0);
        z = __builtin_amdgcn_mfma_f32_16x16x32_bf16(k1, qb[g][1], z, 0, 0, 0);
        s4v pv;
        #pragma unroll
        for (int r = 0; r < 4; ++r) {
          float p = __builtin_amdgcn_exp2f(z[r]);
          lp[g] += p;
          union { float f; unsigned u; } cv; cv.f = p;
          pv[r] = (short)(cv.u >> 16);
        }
        *(s4v*)(myP + (g * 16 + fm) * 72 + s * 16 + quad * 4) = pv;
      }
    }
    asm volatile("s_waitcnt lgkmcnt(0)" ::: "memory");
    #pragma unroll
    for (int h = 0; h < 2; ++h) {
      frag8 pf[4];
      #pragma unroll
      for (int g = 0; g < 4; ++g)
        pf[g] = *(const frag8*)(myP + (g * 16 + fm) * 72 + h * 32 + quad * 8);
      #pragma unroll
      for (int nt = 0; nt < 4; ++nt) {
        frag8 vf = *(const frag8*)(Vc + (nt * 2 + h) * 512 + lane * 8);
        #pragma unroll
        for (int g = 0; g < 4; ++g)
          O[g][nt] = __builtin_amdgcn_mfma_f32_16x16x32_bf16(pf[g], vf, O[g][nt], 0, 0, 0);
      }
    }
    __syncthreads();
  }

  float rl[4][4];
  #pragma unroll
  for (int g = 0; g < 4; ++g) {
    float v = lp[g];
    v += __shfl_xor(v, 16, 64);
    v += __shfl_xor(v, 32, 64);
    float inv = 1.f / v;
    #pragma unroll
    for (int r = 0; r < 4; ++r) rl[g][r] = __shfl(inv, quad * 4 + r, 16);
  }
  const int b = bh >> 4, h = bh & 15;
  #pragma unroll
  for (int g = 0; g < 4; ++g)
    #pragma unroll
    for (int nt = 0; nt < 4; ++nt)
      #pragma unroll
      for (int r = 0; r < 4; ++r) {
        int row = b * 1024 + q0 + g * 16 + quad * 4 + r;  // gathered: [b*S+s][h*64+d]
        int col = h * 64 + nt * 16 + fm;
        Ctx[(size_t)row * 1024 + col] = f2bf(O[g][nt][r] * rl[g][r]);
      }
}

extern "C" void kernel_launch(void* const* d_in, const int* in_sizes, int n_in,
                              void* d_out, int out_size, void* d_ws, size_t ws_size,
                              hipStream_t stream) {
  const float* hs = (const float*)d_in[0];
  const float* wq = (const float*)d_in[1];
  const float* wk = (const float*)d_in[2];
  const float* wv = (const float*)d_in[3];
  const float* wo = (const float*)d_in[4];
  const float* bo = (const float*)d_in[5];
  float* out = (float*)d_out;

  char* wp = (char*)d_ws;
  const size_t MB16 = (size_t)Mm * Ee * 2;   // 16 MiB
  const size_t MB2  = (size_t)Ee * Ee * 2;   // 2 MiB
  short* Xb  = (short*)wp; wp += MB16;
  short* Wqt = (short*)wp; wp += MB2;   // Wqt/Wkt/Wvt/Wot contiguous = [4096][1024]
  short* Wkt = (short*)wp; wp += MB2;
  short* Wvt = (short*)wp; wp += MB2;
  short* Wot = (short*)wp; wp += MB2;
  short* Qb  = (short*)wp; wp += MB16;
  short* Kb  = (short*)wp; wp += MB16;
  short* Vb  = (short*)wp; wp += MB16;
  short* Vt  = (short*)wp; wp += MB16;
  short* Ctx = (short*)wp; wp += MB16;

  // 1. hidden -> bf16
  cvt_kernel<<<(Mm * Ee / 4 + 255) / 256, 256, 0, stream>>>(hs, Xb, Mm * Ee / 4);
  // 2. all 4 weights -> bf16 transposed [out][in], one launch
  transpose_cvt4<<<dim3(32, 32, 4), 256, 0, stream>>>(wq, wk, wv, wo, Wqt);
  // 3. fused QKV projection: 128x256-tile counted schedule, 768 blocks = 3 rounds
  gemm_v5<0, 12><<<768, 512, 0, stream>>>(Xb, Wqt, Qb, Kb, Vb, nullptr);
  // 4. V -> Vt per head (r8's fused-transpose epilogue was WRONG under the reshape
  //    quirk — h lives in row bits; dedicated transpose restored)
  transpose_v<<<dim3(16, 128), 256, 0, stream>>>(Vb, Vt);
  // 5. attention -> gathered ctx (bf16); grid x=bh keeps same-bh blocks on one XCD
  attn_kernel<<<dim3(128, 4), 256, 0, stream>>>(Qb, Kb, Vt, Ctx);
  // 6. output projection + bias: same v5 structure, 256 blocks = exactly 1 round
  gemm_v5<1, 4><<<256, 512, 0, stream>>>(Ctx, Wot, out, nullptr, nullptr, bo);
}